// Round 1
// baseline (3882.232 us; speedup 1.0000x reference)
//
#include <hip/hip_runtime.h>
#include <math.h>

// Problem constants
#define BB   8
#define LL   512
#define DD   768
#define G4   3072      // 4*D
#define NW   3
#define NLAB 9
#define MM   4096      // B*L

// workspace layout (float offsets)
#define OFF_G  ((size_t)0)
#define SZ_G   ((size_t)NW*MM*G4)        // 37,748,736 floats
#define OFF_H  (OFF_G + SZ_G)
#define SZ_H   ((size_t)2*NW*MM*DD)      // 18,874,368 floats (ping-pong)
#define OFF_C  (OFF_H + SZ_H)
#define SZ_C   ((size_t)NW*MM*DD)        // 9,437,184 floats
// total = 66,060,288 floats = 252 MiB

__device__ __forceinline__ float sigm(float x) { return 1.0f / (1.0f + expf(-x)); }

// ---------------------------------------------------------------------------
// Tiled fp32 GEMM, 128x128 macro-tile (MODE 0) or 128x(32 cells x 4 gates)
// (MODE 1), 256 threads, 8x8 per-thread micro-tile, interleaved cols/rows
// (stride 16) so LDS reads are conflict-free.
//
// MODE 0: G[k] = x @ W_ih[k]^T + (b_ih[k]+b_hh[k])          (per-window z)
// MODE 1: gates = h_prev[k] @ W_hh[k]^T ; fused LSTM cell epilogue reading
//         shifted G[k], updating c in place, writing h_next[k].
// ---------------------------------------------------------------------------
template<int MODE>
__global__ __launch_bounds__(256)
void k_gemm(const float* __restrict__ A,     // MODE0: x ; MODE1: h_prev base
            const float* __restrict__ W,     // MODE0: W_ih ; MODE1: W_hh
            const float* __restrict__ bih,
            const float* __restrict__ bhh,
            float* __restrict__ Gbuf,        // MODE0: out ; MODE1: in (shifted)
            float* __restrict__ hnext,       // MODE1 out
            float* __restrict__ cbuf,        // MODE1 in/out
            int kmin, int s)
{
    const int k  = kmin + blockIdx.z;
    const float* Wk = W + (size_t)k * G4 * DD;
    const int r0 = blockIdx.x * 128;
    const int j0 = blockIdx.y * ((MODE == 0) ? 128 : 32);
    const int tid = threadIdx.x;
    const int tx = tid & 15, ty = tid >> 4;

    __shared__ float As[128][17];
    __shared__ float Bs[16][129];

    const float* Abase = (MODE == 0) ? A : (A + (size_t)k * MM * DD);

    float acc[8][8];
#pragma unroll
    for (int i = 0; i < 8; ++i)
#pragma unroll
        for (int m = 0; m < 8; ++m) acc[i][m] = 0.0f;

    for (int k0 = 0; k0 < DD; k0 += 16) {
        // ---- stage A tile: rows r0..r0+127, cols k0..k0+15 ----
#pragma unroll
        for (int i = 0; i < 2; ++i) {
            int idx = tid + i * 256;            // 512 float4 loads
            int row = idx >> 2, kq = idx & 3;
            const float4 v = *reinterpret_cast<const float4*>(
                Abase + (size_t)(r0 + row) * DD + k0 + kq * 4);
            As[row][kq * 4 + 0] = v.x;
            As[row][kq * 4 + 1] = v.y;
            As[row][kq * 4 + 2] = v.z;
            As[row][kq * 4 + 3] = v.w;
        }
        // ---- stage B tile (transposed in LDS): 128 W-rows, cols k0..k0+15 ----
#pragma unroll
        for (int i = 0; i < 2; ++i) {
            int idx = tid + i * 256;
            int p = idx >> 2, kq = idx & 3;
            int j;
            if (MODE == 0) {
                j = j0 + p;                      // plain column block
            } else {
                int g = p >> 5, cc = p & 31;     // 4 gates x 32 cells
                j = g * DD + j0 + cc;
            }
            const float4 v = *reinterpret_cast<const float4*>(
                Wk + (size_t)j * DD + k0 + kq * 4);
            Bs[kq * 4 + 0][p] = v.x;
            Bs[kq * 4 + 1][p] = v.y;
            Bs[kq * 4 + 2][p] = v.z;
            Bs[kq * 4 + 3][p] = v.w;
        }
        __syncthreads();

#pragma unroll
        for (int kk = 0; kk < 16; ++kk) {
            float a[8], b[8];
#pragma unroll
            for (int i = 0; i < 8; ++i) a[i] = As[ty + 16 * i][kk];
#pragma unroll
            for (int m = 0; m < 8; ++m) b[m] = Bs[kk][tx + 16 * m];
#pragma unroll
            for (int i = 0; i < 8; ++i)
#pragma unroll
                for (int m = 0; m < 8; ++m)
                    acc[i][m] = fmaf(a[i], b[m], acc[i][m]);
        }
        __syncthreads();
    }

    if (MODE == 0) {
        float* Gk = Gbuf + (size_t)k * MM * G4;
#pragma unroll
        for (int m = 0; m < 8; ++m) {
            int j = j0 + tx + 16 * m;
            float bsum = bih[k * G4 + j] + bhh[k * G4 + j];
#pragma unroll
            for (int i = 0; i < 8; ++i) {
                int r = r0 + ty + 16 * i;
                Gk[(size_t)r * G4 + j] = acc[i][m] + bsum;
            }
        }
    } else {
        const float* Gk = Gbuf + (size_t)k * MM * G4;
        const float* hp = Abase;                       // h_prev[k]
        float* hn = hnext + (size_t)k * MM * DD;
        float* ck = cbuf + (size_t)k * MM * DD;
        const int hw = k + 1;                          // half window 1,2,3
#pragma unroll
        for (int i = 0; i < 8; ++i) {
            int r = r0 + ty + 16 * i;
            int l = r & (LL - 1);
            int pos = l - hw + s;
            bool valid = (pos >= 0) && (pos < LL);
            int posc = min(max(pos, 0), LL - 1);
            size_t rowG = (size_t)(r - l + posc) * G4;
#pragma unroll
            for (int half = 0; half < 2; ++half) {
                int n = j0 + tx + 16 * half;
                // per-thread: all 4 gates of this cell live in acc registers
                float gi = sigm (acc[i][0 + half] + Gk[rowG + 0 * DD + n]);
                float gf = sigm (acc[i][2 + half] + Gk[rowG + 1 * DD + n]);
                float gg = tanhf(acc[i][4 + half] + Gk[rowG + 2 * DD + n]);
                float go = sigm (acc[i][6 + half] + Gk[rowG + 3 * DD + n]);
                size_t off = (size_t)r * DD + n;
                float cold = ck[off];
                float cnew = gf * cold + gi * gg;
                float hnew = go * tanhf(cnew);
                if (valid) { hn[off] = hnew; ck[off] = cnew; }
                else       { hn[off] = hp[off]; }      // carry state through
            }
        }
    }
}

// ---------------------------------------------------------------------------
// Step 0 (t=0): h=c=0 so gates = shifted G only. Pure elementwise.
// ---------------------------------------------------------------------------
__global__ __launch_bounds__(256)
void k_init(const float* __restrict__ G, float* __restrict__ h0,
            float* __restrict__ c0)
{
    int idx = blockIdx.x * 256 + threadIdx.x;      // [0, NW*MM*DD)
    int k   = idx / (MM * DD);
    int rem = idx - k * (MM * DD);
    int r   = rem / DD;
    int n   = rem - r * DD;
    int l   = r & (LL - 1);
    int hw  = k + 1;
    int pos = l - hw;
    bool valid = (pos >= 0);                        // pos < LL always at t=0
    int posc = valid ? pos : 0;
    const float* Grow = G + (size_t)k * MM * G4 + (size_t)(r - l + posc) * G4 + n;
    float gi = sigm (Grow[0 * DD]);
    float gg = tanhf(Grow[2 * DD]);
    float go = sigm (Grow[3 * DD]);
    float cn = gi * gg;                             // f*0 + i*g
    float hn = go * tanhf(cn);
    size_t off = (size_t)k * MM * DD + (size_t)r * DD + n;
    h0[off] = valid ? hn : 0.0f;
    c0[off] = valid ? cn : 0.0f;
}

// ---------------------------------------------------------------------------
// Epilogue: attn over 3 windows, softmax, residual, 9-label linear.
// One wave (64 lanes) per row; butterfly shuffle reductions.
// ---------------------------------------------------------------------------
__global__ __launch_bounds__(256)
void k_final(const float* __restrict__ x, const float* __restrict__ hfin,
             const float* __restrict__ linw, const float* __restrict__ linb,
             float* __restrict__ out)
{
    int wave = threadIdx.x >> 6, lane = threadIdx.x & 63;
    int r = blockIdx.x * 4 + wave;
    const float* xr = x    + (size_t)r * DD;
    const float* h0 = hfin + (size_t)0 * MM * DD + (size_t)r * DD;
    const float* h1 = hfin + (size_t)1 * MM * DD + (size_t)r * DD;
    const float* h2 = hfin + (size_t)2 * MM * DD + (size_t)r * DD;

    float xe[12], he0[12], he1[12], he2[12];
    float s0 = 0.f, s1 = 0.f, s2 = 0.f;
#pragma unroll
    for (int q = 0; q < 12; ++q) {
        int e = lane + 64 * q;
        xe[q] = xr[e]; he0[q] = h0[e]; he1[q] = h1[e]; he2[q] = h2[e];
        s0 = fmaf(xe[q], he0[q], s0);
        s1 = fmaf(xe[q], he1[q], s1);
        s2 = fmaf(xe[q], he2[q], s2);
    }
#pragma unroll
    for (int d = 1; d < 64; d <<= 1) {
        s0 += __shfl_xor(s0, d, 64);
        s1 += __shfl_xor(s1, d, 64);
        s2 += __shfl_xor(s2, d, 64);
    }
    const float scale = 0.03608439182435161f;      // 1/sqrt(768)
    s0 *= scale; s1 *= scale; s2 *= scale;
    float mx = fmaxf(s0, fmaxf(s1, s2));
    float e0 = expf(s0 - mx), e1 = expf(s1 - mx), e2 = expf(s2 - mx);
    float inv = 1.0f / (e0 + e1 + e2);
    float a0 = e0 * inv, a1 = e1 * inv, a2 = e2 * inv;

    float p[9];
#pragma unroll
    for (int j = 0; j < 9; ++j) p[j] = 0.0f;
#pragma unroll
    for (int q = 0; q < 12; ++q) {
        int e = lane + 64 * q;
        float o = xe[q] + a0 * he0[q] + a1 * he1[q] + a2 * he2[q];
#pragma unroll
        for (int j = 0; j < 9; ++j)
            p[j] = fmaf(o, linw[j * DD + e], p[j]);
    }
#pragma unroll
    for (int j = 0; j < 9; ++j)
#pragma unroll
        for (int d = 1; d < 64; d <<= 1)
            p[j] += __shfl_xor(p[j], d, 64);
    if (lane == 0) {
#pragma unroll
        for (int j = 0; j < 9; ++j)
            out[(size_t)r * NLAB + j] = p[j] + linb[j];
    }
}

// ---------------------------------------------------------------------------
extern "C" void kernel_launch(void* const* d_in, const int* in_sizes, int n_in,
                              void* d_out, int out_size, void* d_ws, size_t ws_size,
                              hipStream_t stream)
{
    const float* x    = (const float*)d_in[0];
    const float* Wih  = (const float*)d_in[1];
    const float* Whh  = (const float*)d_in[2];
    const float* bih  = (const float*)d_in[3];
    const float* bhh  = (const float*)d_in[4];
    const float* linw = (const float*)d_in[5];
    const float* linb = (const float*)d_in[6];
    float* out = (float*)d_out;
    float* ws  = (float*)d_ws;

    float* G = ws + OFF_G;
    float* H = ws + OFF_H;     // 2 ping-pong buffers of NW*MM*DD
    float* C = ws + OFF_C;

    dim3 blk(256);

    // 1) per-window input gates, hoisted out of the time loop
    k_gemm<0><<<dim3(32, 24, 3), blk, 0, stream>>>(
        x, Wih, bih, bhh, G, nullptr, nullptr, 0, 0);

    // 2) t=0: elementwise init (h=c=0 -> no recurrent matmul)
    k_init<<<(NW * MM * DD) / 256, blk, 0, stream>>>(G, H, C);

    // 3) steps s=1..6; windows {3,5,7} aligned at start, batched via grid.z
    for (int s = 1; s < 7; ++s) {
        int kmin = (s < 3) ? 0 : ((s < 5) ? 1 : 2);
        int nact = 3 - kmin;
        const float* hprev = H + (size_t)((s - 1) & 1) * NW * MM * DD;
        float*       hnx   = H + (size_t)(s & 1) * NW * MM * DD;
        k_gemm<1><<<dim3(32, 24, nact), blk, 0, stream>>>(
            hprev, Whh, bih, bhh, G, hnx, C, kmin, s);
    }
    // all windows have odd width -> final h always lands in buffer 0

    // 4) attention over windows + residual + classifier
    k_final<<<MM / 4, blk, 0, stream>>>(x, H, linw, linb, out);
}

// Round 3
// 795.994 us; speedup vs baseline: 4.8772x; 4.8772x over previous
//
#include <hip/hip_runtime.h>
#include <math.h>

// Problem constants
#define BB   8
#define LL   512
#define DD   768
#define G4   3072      // 4*D
#define NW   3
#define NLAB 9
#define MM   4096      // B*L

typedef unsigned short u16;
typedef __attribute__((ext_vector_type(8))) __bf16 bf16x8;
typedef __attribute__((ext_vector_type(4))) float  f32x4;

#define AS1 __attribute__((address_space(1)))
#define AS3 __attribute__((address_space(3)))

// ---------------- workspace layout (bytes) ----------------
// G    fp32 [NW][MM][G4]           150,994,944
// C    fp32 [NW][MM][DD]            37,748,736
// H    bf16 [2][NW][MM][DD]         37,748,736
// xb   bf16 [MM][DD]                 6,291,456
// Wihb bf16 [NW][G4][DD]            14,155,776
// Whhb bf16 [NW][G4][DD]            14,155,776
// total 261,095,424 B (fp32 round used 264 MB and fit)
#define OFF_G    ((size_t)0)
#define OFF_C    ((size_t)150994944)
#define OFF_H    ((size_t)188743680)
#define OFF_XB   ((size_t)226492416)
#define OFF_WIHB ((size_t)232783872)
#define OFF_WHHB ((size_t)246939648)

__device__ __forceinline__ float sigm(float x) { return 1.0f / (1.0f + expf(-x)); }

__device__ __forceinline__ u16 f2bf(float f) {
    union { float f; unsigned u; } v; v.f = f;
    unsigned r = v.u + 0x7FFFu + ((v.u >> 16) & 1u);   // RNE
    return (u16)(r >> 16);
}
__device__ __forceinline__ float bf2f(u16 h) {
    union { unsigned u; float f; } v; v.u = ((unsigned)h) << 16;
    return v.f;
}

// ---------------------------------------------------------------------------
// fp32 -> bf16 bulk convert (float4 in, 8B out per thread)
// ---------------------------------------------------------------------------
__global__ __launch_bounds__(256)
void k_cvt(const float* __restrict__ in, u16* __restrict__ out, int n4)
{
    int i = blockIdx.x * 256 + threadIdx.x;
    if (i >= n4) return;
    float4 v = reinterpret_cast<const float4*>(in)[i];
    ushort4 o;
    o.x = f2bf(v.x); o.y = f2bf(v.y); o.z = f2bf(v.z); o.w = f2bf(v.w);
    reinterpret_cast<ushort4*>(out)[i] = o;
}

// ---------------------------------------------------------------------------
// bf16 MFMA GEMM, 128x128 tile, BK=64, 4 waves (2x2), 4x4 frags of 16x16x32.
// global_load_lds(16B) staging, LDS linear dest + inverse-swizzled source,
// XOR-swizzled ds_read_b128 (slot ^= row&7) -> 2-way (free, m136).
//
// MODE 0: G[k] = xb @ Wihb[k]^T + (b_ih+b_hh)   (fp32 out)
// MODE 1: gates = h_prev[k](bf16) @ Whhb[k]^T ; fused LSTM cell epilogue:
//         reads shifted G[k] (fp32) + c (fp32), writes h_next (bf16), c.
//         B-tile rows remapped so each wave's 4 N-frags = 4 gates x 16 cells.
// ---------------------------------------------------------------------------
template<int MODE>
__global__ __launch_bounds__(256)
void k_mfma(const u16* __restrict__ Ab,      // MODE0: xb ; MODE1: H prev base
            const u16* __restrict__ Wb,      // bf16 weights [NW][G4][DD]
            const float* __restrict__ bih,
            const float* __restrict__ bhh,
            float* __restrict__ Gbuf,
            u16* __restrict__ hnext,
            float* __restrict__ cbuf,
            int kmin, int s)
{
    const int k    = kmin + blockIdx.z;
    const int r0   = blockIdx.x * 128;
    const int tid  = threadIdx.x;
    const int lane = tid & 63;
    const int wid  = tid >> 6;
    const int wm   = wid >> 1, wn = wid & 1;

    __shared__ bf16x8 As[1024];   // [128 rows][8 slots of 16B]  = 16 KB
    __shared__ bf16x8 Bs[1024];   // [128 rows][8 slots]         = 16 KB

    const u16* Asrc = (MODE == 0) ? Ab : (Ab + (size_t)k * MM * DD);
    const u16* Wk   = Wb + (size_t)k * G4 * DD;

    // ---- staging addresses (linear LDS dest, inverse-swizzled source) ----
    const int l3 = lane >> 3;            // 0..7  -> row within 8-row chunk
    const int l7 = lane & 7;             // 0..7  -> stored slot
    const int sg = l7 ^ l3;              // global k-slot (involution)
    const u16* gA[4]; const u16* gB[4];
#pragma unroll
    for (int i = 0; i < 4; ++i) {
        int chunk = wid * 4 + i;         // 16 chunks of 8 rows
        int rowA  = chunk * 8 + l3;      // 0..127
        gA[i] = Asrc + (size_t)(r0 + rowA) * DD + sg * 8;
        int p = chunk * 8 + l3;          // B LDS row = tile column index
        int j;
        if (MODE == 0) {
            j = blockIdx.y * 128 + p;
        } else {
            int cell = (p & 15) + 16 * (p >> 6);   // 32 cells per tile
            int g    = (p >> 4) & 3;               // gate
            j = g * DD + blockIdx.y * 32 + cell;   // W_hh row
        }
        gB[i] = Wk + (size_t)j * DD + sg * 8;
    }

    f32x4 acc[4][4];
#pragma unroll
    for (int a = 0; a < 4; ++a)
#pragma unroll
        for (int b = 0; b < 4; ++b) acc[a][b] = (f32x4)0.0f;

    const int c15 = lane & 15;
    const int khi = lane >> 4;           // 0..3

    for (int k0 = 0; k0 < DD; k0 += 64) {
#pragma unroll
        for (int i = 0; i < 4; ++i) {
            __builtin_amdgcn_global_load_lds(
                (const AS1 void*)(gA[i] + k0),
                (AS3 void*)((char*)As + (wid * 4 + i) * 1024), 16, 0, 0);
            __builtin_amdgcn_global_load_lds(
                (const AS1 void*)(gB[i] + k0),
                (AS3 void*)((char*)Bs + (wid * 4 + i) * 1024), 16, 0, 0);
        }
        __syncthreads();

#pragma unroll
        for (int ks = 0; ks < 2; ++ks) {
            bf16x8 af[4], bfr[4];
#pragma unroll
            for (int mi = 0; mi < 4; ++mi) {
                int row  = wm * 64 + mi * 16 + c15;
                int slot = (ks * 4 + khi) ^ (row & 7);
                af[mi] = As[row * 8 + slot];
            }
#pragma unroll
            for (int ni = 0; ni < 4; ++ni) {
                int row  = wn * 64 + ni * 16 + c15;
                int slot = (ks * 4 + khi) ^ (row & 7);
                bfr[ni] = Bs[row * 8 + slot];
            }
#pragma unroll
            for (int mi = 0; mi < 4; ++mi)
#pragma unroll
                for (int ni = 0; ni < 4; ++ni)
                    acc[mi][ni] = __builtin_amdgcn_mfma_f32_16x16x32_bf16(
                        af[mi], bfr[ni], acc[mi][ni], 0, 0, 0);
        }
        __syncthreads();
    }

    // ---- epilogue ----
    if (MODE == 0) {
        float* Gk = Gbuf + (size_t)k * MM * G4;
        const int j0 = blockIdx.y * 128;
#pragma unroll
        for (int ni = 0; ni < 4; ++ni) {
            int j = j0 + wn * 64 + ni * 16 + c15;
            float bsum = bih[k * G4 + j] + bhh[k * G4 + j];
#pragma unroll
            for (int mi = 0; mi < 4; ++mi)
#pragma unroll
                for (int q = 0; q < 4; ++q) {
                    int r = r0 + wm * 64 + mi * 16 + khi * 4 + q;
                    Gk[(size_t)r * G4 + j] = acc[mi][ni][q] + bsum;
                }
        }
    } else {
        const float* Gk = Gbuf + (size_t)k * MM * G4;
        u16*  hn = hnext + (size_t)k * MM * DD;
        const u16* hp = Asrc;
        float* ck = cbuf + (size_t)k * MM * DD;
        const int n  = blockIdx.y * 32 + wn * 16 + c15;   // cell index
        const int hw = k + 1;
#pragma unroll
        for (int mi = 0; mi < 4; ++mi)
#pragma unroll
            for (int q = 0; q < 4; ++q) {
                int r = r0 + wm * 64 + mi * 16 + khi * 4 + q;
                int l = r & (LL - 1);
                int pos = l - hw + s;
                bool valid = (pos >= 0) && (pos < LL);
                int posc = min(max(pos, 0), LL - 1);
                size_t rowG = (size_t)(r - l + posc) * G4;
                float gi = sigm (acc[mi][0][q] + Gk[rowG + 0 * DD + n]);
                float gf = sigm (acc[mi][1][q] + Gk[rowG + 1 * DD + n]);
                float gg = tanhf(acc[mi][2][q] + Gk[rowG + 2 * DD + n]);
                float go = sigm (acc[mi][3][q] + Gk[rowG + 3 * DD + n]);
                size_t off = (size_t)r * DD + n;
                if (valid) {
                    float cold = ck[off];
                    float cnew = gf * cold + gi * gg;
                    ck[off] = cnew;
                    hn[off] = f2bf(go * tanhf(cnew));
                } else {
                    hn[off] = hp[off];           // carry h through
                }
            }
    }
}

// ---------------------------------------------------------------------------
// Step 0 (t=0): h=c=0 -> gates = shifted G only. Elementwise.
// ---------------------------------------------------------------------------
__global__ __launch_bounds__(256)
void k_init(const float* __restrict__ G, u16* __restrict__ h0,
            float* __restrict__ c0)
{
    int idx = blockIdx.x * 256 + threadIdx.x;      // [0, NW*MM*DD)
    int k   = idx / (MM * DD);
    int rem = idx - k * (MM * DD);
    int r   = rem / DD;
    int n   = rem - r * DD;
    int l   = r & (LL - 1);
    int hw  = k + 1;
    int pos = l - hw;
    bool valid = (pos >= 0);
    int posc = valid ? pos : 0;
    const float* Grow = G + (size_t)k * MM * G4 + (size_t)(r - l + posc) * G4 + n;
    float gi = sigm (Grow[0 * DD]);
    float gg = tanhf(Grow[2 * DD]);
    float go = sigm (Grow[3 * DD]);
    float cn = gi * gg;
    float hv = go * tanhf(cn);
    size_t off = (size_t)k * MM * DD + (size_t)r * DD + n;
    h0[off] = valid ? f2bf(hv) : (u16)0;
    c0[off] = valid ? cn : 0.0f;
}

// ---------------------------------------------------------------------------
// Epilogue: attn over 3 windows, softmax, residual, 9-label linear.
// One wave per row; butterfly shuffle reductions. All fp32 math.
// ---------------------------------------------------------------------------
__global__ __launch_bounds__(256)
void k_final(const float* __restrict__ x, const u16* __restrict__ hfin,
             const float* __restrict__ linw, const float* __restrict__ linb,
             float* __restrict__ out)
{
    int wave = threadIdx.x >> 6, lane = threadIdx.x & 63;
    int r = blockIdx.x * 4 + wave;
    const float* xr = x + (size_t)r * DD;
    const u16* h0 = hfin + (size_t)0 * MM * DD + (size_t)r * DD;
    const u16* h1 = hfin + (size_t)1 * MM * DD + (size_t)r * DD;
    const u16* h2 = hfin + (size_t)2 * MM * DD + (size_t)r * DD;

    float xe[12], he0[12], he1[12], he2[12];
    float s0 = 0.f, s1 = 0.f, s2 = 0.f;
#pragma unroll
    for (int q = 0; q < 12; ++q) {
        int e = lane + 64 * q;
        xe[q] = xr[e];
        he0[q] = bf2f(h0[e]); he1[q] = bf2f(h1[e]); he2[q] = bf2f(h2[e]);
        s0 = fmaf(xe[q], he0[q], s0);
        s1 = fmaf(xe[q], he1[q], s1);
        s2 = fmaf(xe[q], he2[q], s2);
    }
#pragma unroll
    for (int d = 1; d < 64; d <<= 1) {
        s0 += __shfl_xor(s0, d, 64);
        s1 += __shfl_xor(s1, d, 64);
        s2 += __shfl_xor(s2, d, 64);
    }
    const float scale = 0.03608439182435161f;      // 1/sqrt(768)
    s0 *= scale; s1 *= scale; s2 *= scale;
    float mx = fmaxf(s0, fmaxf(s1, s2));
    float e0 = expf(s0 - mx), e1 = expf(s1 - mx), e2 = expf(s2 - mx);
    float inv = 1.0f / (e0 + e1 + e2);
    float a0 = e0 * inv, a1 = e1 * inv, a2 = e2 * inv;

    float p[9];
#pragma unroll
    for (int j = 0; j < 9; ++j) p[j] = 0.0f;
#pragma unroll
    for (int q = 0; q < 12; ++q) {
        int e = lane + 64 * q;
        float o = xe[q] + a0 * he0[q] + a1 * he1[q] + a2 * he2[q];
#pragma unroll
        for (int j = 0; j < 9; ++j)
            p[j] = fmaf(o, linw[j * DD + e], p[j]);
    }
#pragma unroll
    for (int j = 0; j < 9; ++j)
#pragma unroll
        for (int d = 1; d < 64; d <<= 1)
            p[j] += __shfl_xor(p[j], d, 64);
    if (lane == 0) {
#pragma unroll
        for (int j = 0; j < 9; ++j)
            out[(size_t)r * NLAB + j] = p[j] + linb[j];
    }
}

// ---------------------------------------------------------------------------
extern "C" void kernel_launch(void* const* d_in, const int* in_sizes, int n_in,
                              void* d_out, int out_size, void* d_ws, size_t ws_size,
                              hipStream_t stream)
{
    const float* x    = (const float*)d_in[0];
    const float* Wih  = (const float*)d_in[1];
    const float* Whh  = (const float*)d_in[2];
    const float* bih  = (const float*)d_in[3];
    const float* bhh  = (const float*)d_in[4];
    const float* linw = (const float*)d_in[5];
    const float* linb = (const float*)d_in[6];
    float* out = (float*)d_out;
    char*  ws  = (char*)d_ws;

    float* G    = (float*)(ws + OFF_G);
    float* C    = (float*)(ws + OFF_C);
    u16*   H    = (u16*)  (ws + OFF_H);     // 2 ping-pong bufs of NW*MM*DD
    u16*   xb   = (u16*)  (ws + OFF_XB);
    u16*   Wihb = (u16*)  (ws + OFF_WIHB);
    u16*   Whhb = (u16*)  (ws + OFF_WHHB);

    dim3 blk(256);

    // 0) operand conversion to bf16
    k_cvt<<<(MM * DD / 4 + 255) / 256, blk, 0, stream>>>(x, xb, MM * DD / 4);
    k_cvt<<<(NW * G4 * DD / 4 + 255) / 256, blk, 0, stream>>>(Wih, Wihb, NW * G4 * DD / 4);
    k_cvt<<<(NW * G4 * DD / 4 + 255) / 256, blk, 0, stream>>>(Whh, Whhb, NW * G4 * DD / 4);

    // 1) per-window input gates, hoisted out of the time loop
    k_mfma<0><<<dim3(32, 24, 3), blk, 0, stream>>>(
        xb, Wihb, bih, bhh, G, nullptr, nullptr, 0, 0);

    // 2) t=0: elementwise init (h=c=0 -> no recurrent matmul)
    k_init<<<(NW * MM * DD) / 256, blk, 0, stream>>>(G, H, C);

    // 3) steps s=1..6; windows {3,5,7} aligned at start, batched via grid.z
    for (int s = 1; s < 7; ++s) {
        int kmin = (s < 3) ? 0 : ((s < 5) ? 1 : 2);
        int nact = 3 - kmin;
        u16* hprev = H + (size_t)((s - 1) & 1) * NW * MM * DD;
        u16* hnx   = H + (size_t)(s & 1) * NW * MM * DD;
        k_mfma<1><<<dim3(32, 24, nact), blk, 0, stream>>>(
            hprev, Whhb, nullptr, nullptr, G, hnx, C, kmin, s);
    }
    // odd window widths -> final h lands in buffer 0

    // 4) attention over windows + residual + classifier
    k_final<<<MM / 4, blk, 0, stream>>>(x, H, linw, linb, out);
}

// Round 5
// 778.051 us; speedup vs baseline: 4.9897x; 1.0231x over previous
//
#include <hip/hip_runtime.h>
#include <math.h>

// Problem constants
#define BB   8
#define LL   512
#define DD   768
#define G4   3072      // 4*D
#define NW   3
#define NLAB 9
#define MM   4096      // B*L

typedef unsigned short u16;
typedef __attribute__((ext_vector_type(8))) __bf16 bf16x8;
typedef __attribute__((ext_vector_type(4))) float  f32x4;

#define AS1 __attribute__((address_space(1)))
#define AS3 __attribute__((address_space(3)))

// ---------------- workspace layout (bytes) ----------------
// Gp   bf16 [NW][MM][DD][4]  (gate-packed: i,f,g,o per cell)   75,497,472
// C    fp32 [NW][MM][DD]                                       37,748,736
// H    bf16 [2][NW][MM][DD]                                    37,748,736
// xb   bf16 [MM][DD]                                            6,291,456
// Wihb bf16 [NW][G4][DD]                                       14,155,776
// Whhb bf16 [NW][G4][DD]                                       14,155,776
// total 185,597,952 B (round-2 used 261 MB and fit)
#define OFF_G    ((size_t)0)
#define OFF_C    ((size_t)75497472)
#define OFF_H    ((size_t)113246208)
#define OFF_XB   ((size_t)150994944)
#define OFF_WIHB ((size_t)157286400)
#define OFF_WHHB ((size_t)171442176)

__device__ __forceinline__ float sigm(float x) { return 1.0f / (1.0f + expf(-x)); }

__device__ __forceinline__ u16 f2bf(float f) {
    union { float f; unsigned u; } v; v.f = f;
    unsigned r = v.u + 0x7FFFu + ((v.u >> 16) & 1u);   // RNE
    return (u16)(r >> 16);
}
__device__ __forceinline__ float bf2f(u16 h) {
    union { unsigned u; float f; } v; v.u = ((unsigned)h) << 16;
    return v.f;
}

// ---------------------------------------------------------------------------
// Fused fp32 -> bf16 convert for x, W_ih, W_hh (one launch)
// ---------------------------------------------------------------------------
__global__ __launch_bounds__(256)
void k_cvt3(const float* __restrict__ a, const float* __restrict__ b,
            const float* __restrict__ c,
            u16* __restrict__ oa, u16* __restrict__ ob, u16* __restrict__ oc,
            int na4, int nb4, int nc4)
{
    int i = blockIdx.x * 256 + threadIdx.x;
    const float* src; u16* dst; int j;
    if (i < na4)                  { src = a; dst = oa; j = i; }
    else if (i < na4 + nb4)       { src = b; dst = ob; j = i - na4; }
    else if (i < na4 + nb4 + nc4) { src = c; dst = oc; j = i - na4 - nb4; }
    else return;
    float4 v = reinterpret_cast<const float4*>(src)[j];
    ushort4 o;
    o.x = f2bf(v.x); o.y = f2bf(v.y); o.z = f2bf(v.z); o.w = f2bf(v.w);
    reinterpret_cast<ushort4*>(dst)[j] = o;
}

// ---------------------------------------------------------------------------
// bf16 MFMA GEMM, 128x128 tile, BK=64, 4 waves (2x2), 4x4 frags of 16x16x32.
// global_load_lds(16B) staging, LDS linear dest + inverse-swizzled source,
// XOR-swizzled ds_read_b128 (slot ^= row&7) -> 2-way (free; verified 0
// bank-conflict cycles in round 3).
//
// Both modes use the gate-remapped B tile: 128 W-rows = 4 gates x 32 cells,
// so each thread's 4 N-frags are the 4 gates (i,f,g,o) of one cell.
//
// MODE 0: Gp[k][r][n][0..3] = bf16(x @ W_ih[k]^T + b_ih + b_hh)  (ushort4
//         coalesced store) + fused t=0 cell init: h0/c0 written at the
//         shifted row (l+hw) mod 512 (wrapped rows get zeros).
// MODE 1: gates = h_prev[k](bf16) @ Whhb[k]^T ; fused LSTM cell epilogue:
//         one 8B packed-G load per row, c fp32 in-place, h_next bf16.
// ---------------------------------------------------------------------------
template<int MODE>
__global__ __launch_bounds__(256)
void k_mfma(const u16* __restrict__ Ab,      // MODE0: xb ; MODE1: H prev base
            const u16* __restrict__ Wb,      // bf16 weights [NW][G4][DD]
            const float* __restrict__ bih,
            const float* __restrict__ bhh,
            u16* __restrict__ Gp,            // packed gates [NW][MM][DD][4]
            u16* __restrict__ hnext,
            float* __restrict__ cbuf,
            int kmin, int s)
{
    const int k    = kmin + blockIdx.z;
    const int r0   = blockIdx.x * 128;
    const int tid  = threadIdx.x;
    const int lane = tid & 63;
    const int wid  = tid >> 6;
    const int wm   = wid >> 1, wn = wid & 1;

    __shared__ bf16x8 As[1024];   // [128 rows][8 slots of 16B]  = 16 KB
    __shared__ bf16x8 Bs[1024];   // [128 rows][8 slots]         = 16 KB

    const u16* Asrc = (MODE == 0) ? Ab : (Ab + (size_t)k * MM * DD);
    const u16* Wk   = Wb + (size_t)k * G4 * DD;

    // ---- staging addresses (linear LDS dest, inverse-swizzled source) ----
    const int l3 = lane >> 3;            // 0..7  -> row within 8-row chunk
    const int l7 = lane & 7;             // 0..7  -> stored slot
    const int sg = l7 ^ l3;              // global k-slot (involution)
    const u16* gA[4]; const u16* gB[4];
#pragma unroll
    for (int i = 0; i < 4; ++i) {
        int chunk = wid * 4 + i;         // 16 chunks of 8 rows
        int rowA  = chunk * 8 + l3;      // 0..127
        gA[i] = Asrc + (size_t)(r0 + rowA) * DD + sg * 8;
        int p    = chunk * 8 + l3;       // B LDS row
        int cell = (p & 15) + 16 * (p >> 6);   // 32 cells per tile
        int g    = (p >> 4) & 3;               // gate
        int j    = g * DD + blockIdx.y * 32 + cell;
        gB[i] = Wk + (size_t)j * DD + sg * 8;
    }

    f32x4 acc[4][4];
#pragma unroll
    for (int a = 0; a < 4; ++a)
#pragma unroll
        for (int b = 0; b < 4; ++b) acc[a][b] = (f32x4)0.0f;

    const int c15 = lane & 15;
    const int khi = lane >> 4;           // 0..3

    for (int k0 = 0; k0 < DD; k0 += 64) {
#pragma unroll
        for (int i = 0; i < 4; ++i) {
            __builtin_amdgcn_global_load_lds(
                (const AS1 void*)(gA[i] + k0),
                (AS3 void*)((char*)As + (wid * 4 + i) * 1024), 16, 0, 0);
            __builtin_amdgcn_global_load_lds(
                (const AS1 void*)(gB[i] + k0),
                (AS3 void*)((char*)Bs + (wid * 4 + i) * 1024), 16, 0, 0);
        }
        __syncthreads();

#pragma unroll
        for (int ks = 0; ks < 2; ++ks) {
            bf16x8 af[4], bfr[4];
#pragma unroll
            for (int mi = 0; mi < 4; ++mi) {
                int row  = wm * 64 + mi * 16 + c15;
                int slot = (ks * 4 + khi) ^ (row & 7);
                af[mi] = As[row * 8 + slot];
            }
#pragma unroll
            for (int ni = 0; ni < 4; ++ni) {
                int row  = wn * 64 + ni * 16 + c15;
                int slot = (ks * 4 + khi) ^ (row & 7);
                bfr[ni] = Bs[row * 8 + slot];
            }
#pragma unroll
            for (int mi = 0; mi < 4; ++mi)
#pragma unroll
                for (int ni = 0; ni < 4; ++ni)
                    acc[mi][ni] = __builtin_amdgcn_mfma_f32_16x16x32_bf16(
                        af[mi], bfr[ni], acc[mi][ni], 0, 0, 0);
        }
        __syncthreads();
    }

    // ---- epilogue ----
    const int n  = blockIdx.y * 32 + wn * 16 + c15;   // cell index
    const int hw = k + 1;                             // half window 1,2,3

    if (MODE == 0) {
        u16*   Gk = Gp    + ((size_t)k * MM * DD) * 4;
        u16*   h0 = hnext + (size_t)k * MM * DD;
        float* c0 = cbuf  + (size_t)k * MM * DD;
        const float bs0 = bih[k * G4 + 0 * DD + n] + bhh[k * G4 + 0 * DD + n];
        const float bs1 = bih[k * G4 + 1 * DD + n] + bhh[k * G4 + 1 * DD + n];
        const float bs2 = bih[k * G4 + 2 * DD + n] + bhh[k * G4 + 2 * DD + n];
        const float bs3 = bih[k * G4 + 3 * DD + n] + bhh[k * G4 + 3 * DD + n];
#pragma unroll
        for (int mi = 0; mi < 4; ++mi)
#pragma unroll
            for (int q = 0; q < 4; ++q) {
                int r = r0 + wm * 64 + mi * 16 + khi * 4 + q;
                float p0 = acc[mi][0][q] + bs0;
                float p1 = acc[mi][1][q] + bs1;
                float p2 = acc[mi][2][q] + bs2;
                float p3 = acc[mi][3][q] + bs3;
                ushort4 pk;
                pk.x = f2bf(p0); pk.y = f2bf(p1); pk.z = f2bf(p2); pk.w = f2bf(p3);
                *reinterpret_cast<ushort4*>(Gk + ((size_t)r * DD + n) * 4) = pk;
                // fused t=0 init at shifted row (l+hw) mod LL
                int l  = r & (LL - 1);
                bool ok = (l + hw) < LL;
                int rt = ok ? (r + hw) : (r + hw - LL);
                float iv = sigm(p0), gv = tanhf(p2), ov = sigm(p3);
                float cn = iv * gv;
                float hv = ov * tanhf(cn);
                size_t offt = (size_t)rt * DD + n;
                c0[offt] = ok ? cn : 0.0f;
                h0[offt] = ok ? f2bf(hv) : (u16)0;
            }
    } else {
        const u16* Gk = Gp + ((size_t)k * MM * DD) * 4;
        u16*  hn = hnext + (size_t)k * MM * DD;
        const u16* hp = Asrc;
        float* ck = cbuf + (size_t)k * MM * DD;
#pragma unroll
        for (int mi = 0; mi < 4; ++mi)
#pragma unroll
            for (int q = 0; q < 4; ++q) {
                int r = r0 + wm * 64 + mi * 16 + khi * 4 + q;
                int l = r & (LL - 1);
                int pos = l - hw + s;
                bool valid = (pos >= 0) && (pos < LL);
                int posc = min(max(pos, 0), LL - 1);
                ushort4 g4 = *reinterpret_cast<const ushort4*>(
                    Gk + ((size_t)(r - l + posc) * DD + n) * 4);
                float gi = sigm (acc[mi][0][q] + bf2f(g4.x));
                float gf = sigm (acc[mi][1][q] + bf2f(g4.y));
                float gg = tanhf(acc[mi][2][q] + bf2f(g4.z));
                float go = sigm (acc[mi][3][q] + bf2f(g4.w));
                size_t off = (size_t)r * DD + n;
                if (valid) {
                    float cold = ck[off];
                    float cnew = gf * cold + gi * gg;
                    ck[off] = cnew;
                    hn[off] = f2bf(go * tanhf(cnew));
                } else {
                    hn[off] = hp[off];           // carry h through
                }
            }
    }
}

// ---------------------------------------------------------------------------
// Epilogue: attn over 3 windows, softmax, residual, 9-label linear.
// One wave per row; butterfly shuffle reductions. All fp32 math.
// ---------------------------------------------------------------------------
__global__ __launch_bounds__(256)
void k_final(const float* __restrict__ x, const u16* __restrict__ hfin,
             const float* __restrict__ linw, const float* __restrict__ linb,
             float* __restrict__ out)
{
    int wave = threadIdx.x >> 6, lane = threadIdx.x & 63;
    int r = blockIdx.x * 4 + wave;
    const float* xr = x + (size_t)r * DD;
    const u16* h0 = hfin + (size_t)0 * MM * DD + (size_t)r * DD;
    const u16* h1 = hfin + (size_t)1 * MM * DD + (size_t)r * DD;
    const u16* h2 = hfin + (size_t)2 * MM * DD + (size_t)r * DD;

    float xe[12], he0[12], he1[12], he2[12];
    float s0 = 0.f, s1 = 0.f, s2 = 0.f;
#pragma unroll
    for (int q = 0; q < 12; ++q) {
        int e = lane + 64 * q;
        xe[q] = xr[e];
        he0[q] = bf2f(h0[e]); he1[q] = bf2f(h1[e]); he2[q] = bf2f(h2[e]);
        s0 = fmaf(xe[q], he0[q], s0);
        s1 = fmaf(xe[q], he1[q], s1);
        s2 = fmaf(xe[q], he2[q], s2);
    }
#pragma unroll
    for (int d = 1; d < 64; d <<= 1) {
        s0 += __shfl_xor(s0, d, 64);
        s1 += __shfl_xor(s1, d, 64);
        s2 += __shfl_xor(s2, d, 64);
    }
    const float scale = 0.03608439182435161f;      // 1/sqrt(768)
    s0 *= scale; s1 *= scale; s2 *= scale;
    float mx = fmaxf(s0, fmaxf(s1, s2));
    float e0 = expf(s0 - mx), e1 = expf(s1 - mx), e2 = expf(s2 - mx);
    float inv = 1.0f / (e0 + e1 + e2);
    float a0 = e0 * inv, a1 = e1 * inv, a2 = e2 * inv;

    float p[9];
#pragma unroll
    for (int j = 0; j < 9; ++j) p[j] = 0.0f;
#pragma unroll
    for (int q = 0; q < 12; ++q) {
        int e = lane + 64 * q;
        float o = xe[q] + a0 * he0[q] + a1 * he1[q] + a2 * he2[q];
#pragma unroll
        for (int j = 0; j < 9; ++j)
            p[j] = fmaf(o, linw[j * DD + e], p[j]);
    }
#pragma unroll
    for (int j = 0; j < 9; ++j)
#pragma unroll
        for (int d = 1; d < 64; d <<= 1)
            p[j] += __shfl_xor(p[j], d, 64);
    if (lane == 0) {
#pragma unroll
        for (int j = 0; j < 9; ++j)
            out[(size_t)r * NLAB + j] = p[j] + linb[j];
    }
}

// ---------------------------------------------------------------------------
extern "C" void kernel_launch(void* const* d_in, const int* in_sizes, int n_in,
                              void* d_out, int out_size, void* d_ws, size_t ws_size,
                              hipStream_t stream)
{
    const float* x    = (const float*)d_in[0];
    const float* Wih  = (const float*)d_in[1];
    const float* Whh  = (const float*)d_in[2];
    const float* bih  = (const float*)d_in[3];
    const float* bhh  = (const float*)d_in[4];
    const float* linw = (const float*)d_in[5];
    const float* linb = (const float*)d_in[6];
    float* out = (float*)d_out;
    char*  ws  = (char*)d_ws;

    u16*   Gp   = (u16*)  (ws + OFF_G);
    float* C    = (float*)(ws + OFF_C);
    u16*   H    = (u16*)  (ws + OFF_H);     // 2 ping-pong bufs of NW*MM*DD
    u16*   xb   = (u16*)  (ws + OFF_XB);
    u16*   Wihb = (u16*)  (ws + OFF_WIHB);
    u16*   Whhb = (u16*)  (ws + OFF_WHHB);

    dim3 blk(256);

    // 0) operand conversion to bf16 (single fused launch)
    const int na4 = MM * DD / 4;
    const int nb4 = NW * G4 * DD / 4;
    k_cvt3<<<(na4 + 2 * nb4 + 255) / 256, blk, 0, stream>>>(
        x, Wih, Whh, xb, Wihb, Whhb, na4, nb4, nb4);

    // 1) input gates (packed bf16) + fused t=0 cell init -> H buf0, C
    k_mfma<0><<<dim3(32, 24, 3), blk, 0, stream>>>(
        xb, Wihb, bih, bhh, Gp, H, C, 0, 0);

    // 2) steps s=1..6; windows {3,5,7} aligned at start, batched via grid.z
    for (int s = 1; s < 7; ++s) {
        int kmin = (s < 3) ? 0 : ((s < 5) ? 1 : 2);
        int nact = 3 - kmin;
        u16* hprev = H + (size_t)((s - 1) & 1) * NW * MM * DD;
        u16* hnx   = H + (size_t)(s & 1) * NW * MM * DD;
        k_mfma<1><<<dim3(32, 24, nact), blk, 0, stream>>>(
            hprev, Whhb, nullptr, nullptr, Gp, hnx, C, kmin, s);
    }
    // odd window widths -> final h lands in buffer 0

    // 3) attention over windows + residual + classifier
    k_final<<<MM / 4, blk, 0, stream>>>(x, H, linw, linb, out);
}

// Round 6
// 712.247 us; speedup vs baseline: 5.4507x; 1.0924x over previous
//
#include <hip/hip_runtime.h>
#include <math.h>

// Problem constants
#define BB   8
#define LL   512
#define DD   768
#define G4   3072      // 4*D
#define NW   3
#define NLAB 9
#define MM   4096      // B*L

typedef unsigned short u16;
typedef __attribute__((ext_vector_type(8))) __bf16 bf16x8;
typedef __attribute__((ext_vector_type(4))) float  f32x4;

#define AS1 __attribute__((address_space(1)))
#define AS3 __attribute__((address_space(3)))

// ---------------- workspace layout (bytes) ----------------
// Gp   bf16 [NW][MM][DD][4]  (gate-packed: i,f,g,o per cell)   75,497,472
// C    fp32 [NW][MM][DD]                                       37,748,736
// H    bf16 [2][NW][MM][DD]                                    37,748,736
// xb   bf16 [MM][DD]                                            6,291,456
// Wihb bf16 [NW][G4][DD]                                       14,155,776
// Whhb bf16 [NW][G4][DD]                                       14,155,776
// total 185,597,952 B
#define OFF_G    ((size_t)0)
#define OFF_C    ((size_t)75497472)
#define OFF_H    ((size_t)113246208)
#define OFF_XB   ((size_t)150994944)
#define OFF_WIHB ((size_t)157286400)
#define OFF_WHHB ((size_t)171442176)

// ---- fast hardware transcendentals (v_exp_f32 = 2^x, v_rcp_f32) ----
#if __has_builtin(__builtin_amdgcn_exp2f)
#define FEXP2(x) __builtin_amdgcn_exp2f(x)
#else
#define FEXP2(x) exp2f(x)
#endif
#if __has_builtin(__builtin_amdgcn_rcpf)
#define FRCP(x) __builtin_amdgcn_rcpf(x)
#else
#define FRCP(x) (1.0f / (x))
#endif
#define LOG2E  1.4426950408889634f
#define LOG2E2 2.8853900817779268f

// sigm(x) = 1/(1+e^-x) = rcp(1 + 2^(-x*log2e))          (~3 VALU ops)
__device__ __forceinline__ float sigm(float x) {
    return FRCP(1.0f + FEXP2(-LOG2E * x));
}
// tanh(x) = 1 - 2/(1+e^{2x}) = 1 - 2*rcp(1 + 2^(x*2log2e))  (~4 VALU ops)
// saturates correctly: x->+inf => 1, x->-inf => -1
__device__ __forceinline__ float ftanh(float x) {
    return 1.0f - 2.0f * FRCP(1.0f + FEXP2(LOG2E2 * x));
}

__device__ __forceinline__ u16 f2bf(float f) {
    union { float f; unsigned u; } v; v.f = f;
    unsigned r = v.u + 0x7FFFu + ((v.u >> 16) & 1u);   // RNE
    return (u16)(r >> 16);
}
__device__ __forceinline__ float bf2f(u16 h) {
    union { unsigned u; float f; } v; v.u = ((unsigned)h) << 16;
    return v.f;
}

// ---------------------------------------------------------------------------
// Fused fp32 -> bf16 convert for x, W_ih, W_hh (one launch)
// ---------------------------------------------------------------------------
__global__ __launch_bounds__(256)
void k_cvt3(const float* __restrict__ a, const float* __restrict__ b,
            const float* __restrict__ c,
            u16* __restrict__ oa, u16* __restrict__ ob, u16* __restrict__ oc,
            int na4, int nb4, int nc4)
{
    int i = blockIdx.x * 256 + threadIdx.x;
    const float* src; u16* dst; int j;
    if (i < na4)                  { src = a; dst = oa; j = i; }
    else if (i < na4 + nb4)       { src = b; dst = ob; j = i - na4; }
    else if (i < na4 + nb4 + nc4) { src = c; dst = oc; j = i - na4 - nb4; }
    else return;
    float4 v = reinterpret_cast<const float4*>(src)[j];
    ushort4 o;
    o.x = f2bf(v.x); o.y = f2bf(v.y); o.z = f2bf(v.z); o.w = f2bf(v.w);
    reinterpret_cast<ushort4*>(dst)[j] = o;
}

// ---------------------------------------------------------------------------
// bf16 MFMA GEMM, 128x128 tile, BK=64, 4 waves (2x2), 4x4 frags of 16x16x32.
// global_load_lds(16B) staging, LDS linear dest + inverse-swizzled source,
// XOR-swizzled ds_read_b128 (slot ^= row&7) -> 2-way (free; verified 0
// bank-conflict cycles in rounds 3 and 5).
//
// Both modes use the gate-remapped B tile: 128 W-rows = 4 gates x 32 cells,
// so each thread's 4 N-frags are the 4 gates (i,f,g,o) of one cell.
//
// MODE 0: Gp[k][r][n][0..3] = bf16(x @ W_ih[k]^T + b_ih + b_hh)  (ushort4
//         coalesced store) + fused t=0 cell init at shifted row.
// MODE 1: gates = h_prev[k](bf16) @ Whhb[k]^T ; fused LSTM cell epilogue:
//         one 8B packed-G load per row, c fp32 in-place, h_next bf16.
//         Gate nonlinearities via v_exp_f32/v_rcp_f32 (round-5 finding:
//         libm tanhf/expf epilogue was VALU-dominant, VALUBusy 39%).
// ---------------------------------------------------------------------------
template<int MODE>
__global__ __launch_bounds__(256)
void k_mfma(const u16* __restrict__ Ab,      // MODE0: xb ; MODE1: H prev base
            const u16* __restrict__ Wb,      // bf16 weights [NW][G4][DD]
            const float* __restrict__ bih,
            const float* __restrict__ bhh,
            u16* __restrict__ Gp,            // packed gates [NW][MM][DD][4]
            u16* __restrict__ hnext,
            float* __restrict__ cbuf,
            int kmin, int s)
{
    const int k    = kmin + blockIdx.z;
    const int r0   = blockIdx.x * 128;
    const int tid  = threadIdx.x;
    const int lane = tid & 63;
    const int wid  = tid >> 6;
    const int wm   = wid >> 1, wn = wid & 1;

    __shared__ bf16x8 As[1024];   // [128 rows][8 slots of 16B]  = 16 KB
    __shared__ bf16x8 Bs[1024];   // [128 rows][8 slots]         = 16 KB

    const u16* Asrc = (MODE == 0) ? Ab : (Ab + (size_t)k * MM * DD);
    const u16* Wk   = Wb + (size_t)k * G4 * DD;

    // ---- staging addresses (linear LDS dest, inverse-swizzled source) ----
    const int l3 = lane >> 3;            // 0..7  -> row within 8-row chunk
    const int l7 = lane & 7;             // 0..7  -> stored slot
    const int sg = l7 ^ l3;              // global k-slot (involution)
    const u16* gA[4]; const u16* gB[4];
#pragma unroll
    for (int i = 0; i < 4; ++i) {
        int chunk = wid * 4 + i;         // 16 chunks of 8 rows
        int rowA  = chunk * 8 + l3;      // 0..127
        gA[i] = Asrc + (size_t)(r0 + rowA) * DD + sg * 8;
        int p    = chunk * 8 + l3;       // B LDS row
        int cell = (p & 15) + 16 * (p >> 6);   // 32 cells per tile
        int g    = (p >> 4) & 3;               // gate
        int j    = g * DD + blockIdx.y * 32 + cell;
        gB[i] = Wk + (size_t)j * DD + sg * 8;
    }

    f32x4 acc[4][4];
#pragma unroll
    for (int a = 0; a < 4; ++a)
#pragma unroll
        for (int b = 0; b < 4; ++b) acc[a][b] = (f32x4)0.0f;

    const int c15 = lane & 15;
    const int khi = lane >> 4;           // 0..3

    for (int k0 = 0; k0 < DD; k0 += 64) {
#pragma unroll
        for (int i = 0; i < 4; ++i) {
            __builtin_amdgcn_global_load_lds(
                (const AS1 void*)(gA[i] + k0),
                (AS3 void*)((char*)As + (wid * 4 + i) * 1024), 16, 0, 0);
            __builtin_amdgcn_global_load_lds(
                (const AS1 void*)(gB[i] + k0),
                (AS3 void*)((char*)Bs + (wid * 4 + i) * 1024), 16, 0, 0);
        }
        __syncthreads();

#pragma unroll
        for (int ks = 0; ks < 2; ++ks) {
            bf16x8 af[4], bfr[4];
#pragma unroll
            for (int mi = 0; mi < 4; ++mi) {
                int row  = wm * 64 + mi * 16 + c15;
                int slot = (ks * 4 + khi) ^ (row & 7);
                af[mi] = As[row * 8 + slot];
            }
#pragma unroll
            for (int ni = 0; ni < 4; ++ni) {
                int row  = wn * 64 + ni * 16 + c15;
                int slot = (ks * 4 + khi) ^ (row & 7);
                bfr[ni] = Bs[row * 8 + slot];
            }
#pragma unroll
            for (int mi = 0; mi < 4; ++mi)
#pragma unroll
                for (int ni = 0; ni < 4; ++ni)
                    acc[mi][ni] = __builtin_amdgcn_mfma_f32_16x16x32_bf16(
                        af[mi], bfr[ni], acc[mi][ni], 0, 0, 0);
        }
        __syncthreads();
    }

    // ---- epilogue ----
    const int n  = blockIdx.y * 32 + wn * 16 + c15;   // cell index
    const int hw = k + 1;                             // half window 1,2,3

    if (MODE == 0) {
        u16*   Gk = Gp    + ((size_t)k * MM * DD) * 4;
        u16*   h0 = hnext + (size_t)k * MM * DD;
        float* c0 = cbuf  + (size_t)k * MM * DD;
        const float bs0 = bih[k * G4 + 0 * DD + n] + bhh[k * G4 + 0 * DD + n];
        const float bs1 = bih[k * G4 + 1 * DD + n] + bhh[k * G4 + 1 * DD + n];
        const float bs2 = bih[k * G4 + 2 * DD + n] + bhh[k * G4 + 2 * DD + n];
        const float bs3 = bih[k * G4 + 3 * DD + n] + bhh[k * G4 + 3 * DD + n];
#pragma unroll
        for (int mi = 0; mi < 4; ++mi)
#pragma unroll
            for (int q = 0; q < 4; ++q) {
                int r = r0 + wm * 64 + mi * 16 + khi * 4 + q;
                float p0 = acc[mi][0][q] + bs0;
                float p1 = acc[mi][1][q] + bs1;
                float p2 = acc[mi][2][q] + bs2;
                float p3 = acc[mi][3][q] + bs3;
                ushort4 pk;
                pk.x = f2bf(p0); pk.y = f2bf(p1); pk.z = f2bf(p2); pk.w = f2bf(p3);
                *reinterpret_cast<ushort4*>(Gk + ((size_t)r * DD + n) * 4) = pk;
                // fused t=0 init at shifted row (l+hw) mod LL
                int l  = r & (LL - 1);
                bool ok = (l + hw) < LL;
                int rt = ok ? (r + hw) : (r + hw - LL);
                float iv = sigm(p0), gv = ftanh(p2), ov = sigm(p3);
                float cn = iv * gv;
                float hv = ov * ftanh(cn);
                size_t offt = (size_t)rt * DD + n;
                c0[offt] = ok ? cn : 0.0f;
                h0[offt] = ok ? f2bf(hv) : (u16)0;
            }
    } else {
        const u16* Gk = Gp + ((size_t)k * MM * DD) * 4;
        u16*  hn = hnext + (size_t)k * MM * DD;
        const u16* hp = Asrc;
        float* ck = cbuf + (size_t)k * MM * DD;
#pragma unroll
        for (int mi = 0; mi < 4; ++mi)
#pragma unroll
            for (int q = 0; q < 4; ++q) {
                int r = r0 + wm * 64 + mi * 16 + khi * 4 + q;
                int l = r & (LL - 1);
                int pos = l - hw + s;
                bool valid = (pos >= 0) && (pos < LL);
                int posc = min(max(pos, 0), LL - 1);
                ushort4 g4 = *reinterpret_cast<const ushort4*>(
                    Gk + ((size_t)(r - l + posc) * DD + n) * 4);
                float gi = sigm (acc[mi][0][q] + bf2f(g4.x));
                float gf = sigm (acc[mi][1][q] + bf2f(g4.y));
                float gg = ftanh(acc[mi][2][q] + bf2f(g4.z));
                float go = sigm (acc[mi][3][q] + bf2f(g4.w));
                size_t off = (size_t)r * DD + n;
                if (valid) {
                    float cold = ck[off];
                    float cnew = gf * cold + gi * gg;
                    ck[off] = cnew;
                    hn[off] = f2bf(go * ftanh(cnew));
                } else {
                    hn[off] = hp[off];           // carry h through
                }
            }
    }
}

// ---------------------------------------------------------------------------
// Epilogue: attn over 3 windows, softmax, residual, 9-label linear.
// One wave per row; butterfly shuffle reductions. All fp32 math.
// ---------------------------------------------------------------------------
__global__ __launch_bounds__(256)
void k_final(const float* __restrict__ x, const u16* __restrict__ hfin,
             const float* __restrict__ linw, const float* __restrict__ linb,
             float* __restrict__ out)
{
    int wave = threadIdx.x >> 6, lane = threadIdx.x & 63;
    int r = blockIdx.x * 4 + wave;
    const float* xr = x + (size_t)r * DD;
    const u16* h0 = hfin + (size_t)0 * MM * DD + (size_t)r * DD;
    const u16* h1 = hfin + (size_t)1 * MM * DD + (size_t)r * DD;
    const u16* h2 = hfin + (size_t)2 * MM * DD + (size_t)r * DD;

    float xe[12], he0[12], he1[12], he2[12];
    float s0 = 0.f, s1 = 0.f, s2 = 0.f;
#pragma unroll
    for (int q = 0; q < 12; ++q) {
        int e = lane + 64 * q;
        xe[q] = xr[e];
        he0[q] = bf2f(h0[e]); he1[q] = bf2f(h1[e]); he2[q] = bf2f(h2[e]);
        s0 = fmaf(xe[q], he0[q], s0);
        s1 = fmaf(xe[q], he1[q], s1);
        s2 = fmaf(xe[q], he2[q], s2);
    }
#pragma unroll
    for (int d = 1; d < 64; d <<= 1) {
        s0 += __shfl_xor(s0, d, 64);
        s1 += __shfl_xor(s1, d, 64);
        s2 += __shfl_xor(s2, d, 64);
    }
    const float scale = 0.03608439182435161f;      // 1/sqrt(768)
    s0 *= scale; s1 *= scale; s2 *= scale;
    float mx = fmaxf(s0, fmaxf(s1, s2));
    float e0 = FEXP2(LOG2E * (s0 - mx));
    float e1 = FEXP2(LOG2E * (s1 - mx));
    float e2 = FEXP2(LOG2E * (s2 - mx));
    float inv = FRCP(e0 + e1 + e2);
    float a0 = e0 * inv, a1 = e1 * inv, a2 = e2 * inv;

    float p[9];
#pragma unroll
    for (int j = 0; j < 9; ++j) p[j] = 0.0f;
#pragma unroll
    for (int q = 0; q < 12; ++q) {
        int e = lane + 64 * q;
        float o = xe[q] + a0 * he0[q] + a1 * he1[q] + a2 * he2[q];
#pragma unroll
        for (int j = 0; j < 9; ++j)
            p[j] = fmaf(o, linw[j * DD + e], p[j]);
    }
#pragma unroll
    for (int j = 0; j < 9; ++j)
#pragma unroll
        for (int d = 1; d < 64; d <<= 1)
            p[j] += __shfl_xor(p[j], d, 64);
    if (lane == 0) {
#pragma unroll
        for (int j = 0; j < 9; ++j)
            out[(size_t)r * NLAB + j] = p[j] + linb[j];
    }
}

// ---------------------------------------------------------------------------
extern "C" void kernel_launch(void* const* d_in, const int* in_sizes, int n_in,
                              void* d_out, int out_size, void* d_ws, size_t ws_size,
                              hipStream_t stream)
{
    const float* x    = (const float*)d_in[0];
    const float* Wih  = (const float*)d_in[1];
    const float* Whh  = (const float*)d_in[2];
    const float* bih  = (const float*)d_in[3];
    const float* bhh  = (const float*)d_in[4];
    const float* linw = (const float*)d_in[5];
    const float* linb = (const float*)d_in[6];
    float* out = (float*)d_out;
    char*  ws  = (char*)d_ws;

    u16*   Gp   = (u16*)  (ws + OFF_G);
    float* C    = (float*)(ws + OFF_C);
    u16*   H    = (u16*)  (ws + OFF_H);     // 2 ping-pong bufs of NW*MM*DD
    u16*   xb   = (u16*)  (ws + OFF_XB);
    u16*   Wihb = (u16*)  (ws + OFF_WIHB);
    u16*   Whhb = (u16*)  (ws + OFF_WHHB);

    dim3 blk(256);

    // 0) operand conversion to bf16 (single fused launch)
    const int na4 = MM * DD / 4;
    const int nb4 = NW * G4 * DD / 4;
    k_cvt3<<<(na4 + 2 * nb4 + 255) / 256, blk, 0, stream>>>(
        x, Wih, Whh, xb, Wihb, Whhb, na4, nb4, nb4);

    // 1) input gates (packed bf16) + fused t=0 cell init -> H buf0, C
    k_mfma<0><<<dim3(32, 24, 3), blk, 0, stream>>>(
        xb, Wihb, bih, bhh, Gp, H, C, 0, 0);

    // 2) steps s=1..6; windows {3,5,7} aligned at start, batched via grid.z
    for (int s = 1; s < 7; ++s) {
        int kmin = (s < 3) ? 0 : ((s < 5) ? 1 : 2);
        int nact = 3 - kmin;
        u16* hprev = H + (size_t)((s - 1) & 1) * NW * MM * DD;
        u16* hnx   = H + (size_t)(s & 1) * NW * MM * DD;
        k_mfma<1><<<dim3(32, 24, nact), blk, 0, stream>>>(
            hprev, Whhb, nullptr, nullptr, Gp, hnx, C, kmin, s);
    }
    // odd window widths -> final h lands in buffer 0

    // 3) attention over windows + residual + classifier
    k_final<<<MM / 4, blk, 0, stream>>>(x, H, linw, linb, out);
}